// Round 12
// baseline (101.807 us; speedup 1.0000x reference)
//
#include <hip/hip_runtime.h>
#include <hip/hip_bf16.h>
#include <stdint.h>

typedef unsigned short ushort_t;
typedef short v8s __attribute__((ext_vector_type(8)));
typedef float f32x4 __attribute__((ext_vector_type(4)));
typedef float f32x16 __attribute__((ext_vector_type(16)));

#define MFMA16(a, b, c) __builtin_amdgcn_mfma_f32_16x16x32_bf16(a, b, c, 0, 0, 0)
#define MFMA32(a, b, c) __builtin_amdgcn_mfma_f32_32x32x16_bf16(a, b, c, 0, 0, 0)

typedef __attribute__((address_space(1))) void gvoid;
typedef __attribute__((address_space(3))) void svoid;

__device__ __forceinline__ void gld16(const void* g, void* s) {
    __builtin_amdgcn_global_load_lds((gvoid*)g, (svoid*)s, 16, 0, 0);
}

__device__ __forceinline__ ushort_t f2bf(float f) {
    union { __hip_bfloat16 b; ushort_t u; } c;
    c.b = __float2bfloat16(f);
    return c.u;
}

__device__ __forceinline__ unsigned f2bf2(float a, float b) {
    union { __hip_bfloat162 b2; unsigned u; } c;
    c.b2 = __float22bfloat162_rn(make_float2(a, b));
    return c.u;
}

// ---------------------------------------------------------------------------
// Kernel 1: transpose W [2048][128] f32 -> WT [384][2048] bf16 (q|k|v rows)
// ---------------------------------------------------------------------------
__global__ void transpose_w(const float* __restrict__ Wq, const float* __restrict__ Wk,
                            const float* __restrict__ Wv, ushort_t* __restrict__ WT) {
    __shared__ float tile[64][132];
    int bid = blockIdx.x;            // 96 = 3 weights x 32 k-blocks
    int w = bid >> 5;
    int k0 = (bid & 31) << 6;
    const float* W = (w == 0) ? Wq : ((w == 1) ? Wk : Wv);
    int tid = threadIdx.x;
    #pragma unroll
    for (int i = 0; i < 8; i++) {
        int row = i * 8 + (tid >> 5);
        int col = (tid & 31) * 4;
        float4 v = *(const float4*)(W + (size_t)(k0 + row) * 128 + col);
        tile[row][col] = v.x; tile[row][col + 1] = v.y;
        tile[row][col + 2] = v.z; tile[row][col + 3] = v.w;
    }
    __syncthreads();
    int n = tid >> 1, kh = (tid & 1) * 32;
    ushort_t* dst = WT + ((size_t)(w * 128 + n)) * 2048 + k0 + kh;
    #pragma unroll
    for (int j = 0; j < 32; j += 4) {
        union { ushort_t u[4]; uint2 v2; } pk;
        #pragma unroll
        for (int e = 0; e < 4; e++) pk.u[e] = f2bf(tile[kh + j + e][n]);
        *(uint2*)(dst + j) = pk.v2;
    }
}

// ---------------------------------------------------------------------------
// Kernel 2: fused QKV projection v12 — minimal-staged-bytes tile (128m x 192n).
// Conservation law: staged = x_bytes*(384/Ntile) + B_bytes*(16384/Mtile).
// (128,192) = 256+192 = 448 MB total (vs 768 MB at R10's (64,128)).
// grid 256 = 128 mtiles x 2 nhalves, 1 block/CU (zero tail); 512 threads =
// 8 waves (2 wr x 4 wc); wave tile 64m x 48n = acc[4][3]; BK=64, 32 iters.
// A: x coalesced f32 reg loads 2-ahead -> cvt_pk -> 8B swizzled ds_write.
// B: gld16 1-ahead, pre-swizzled source. LDS 80 KB dbuf.
// Counted vmcnt(4) at the single per-iter barrier (x loads span barrier).
// (mt,0)/(mt,1) pinned to one XCD (bids differ by 8) -> x L2-shared.
// Blocked output layouts (per batch 524288 elems):
//   q_blk/k_blk: (t>>5)*4096 + (d>>4)*512 + ((d>>3)&1)*256 + (t&31)*8 + (d&7)
//   v_blk:       (t>>4)*2048 + (d>>5)*512 + ((t>>3)&1)*256 + (d&31)*8 + (t&7)
// ---------------------------------------------------------------------------
#define PJ_XLOAD(S, IT)                                                       \
    {                                                                         \
        _Pragma("unroll")                                                     \
        for (int i = 0; i < 4; i++)                                           \
            S[i] = *(const f32x4*)(xsrc[i] + (size_t)(IT) * 256);             \
    }

#define PJ_CVT_WRITE(RS, PAR)                                                 \
    {                                                                         \
        _Pragma("unroll")                                                     \
        for (int i = 0; i < 4; i++) {                                         \
            uint2 p;                                                          \
            p.x = f2bf2(RS[i][0], RS[i][1]);                                  \
            p.y = f2bf2(RS[i][2], RS[i][3]);                                  \
            *(uint2*)((char*)abuf + (PAR) * 16384 + awb[i]) = p;              \
        }                                                                     \
    }

#define PJ_STEP(PAR, IT, RLOAD, RCVT, DOX, DOB)                               \
    {                                                                         \
        if (DOB) {                                                            \
            _Pragma("unroll")                                                 \
            for (int i = 0; i < 3; i++)                                       \
                gld16(bsrc[i] + (size_t)((IT) + 1) * 128,                     \
                      (char*)bbuf + ((PAR) ^ 1) * 24576 + (wid * 3 + i) * 1024); \
        }                                                                     \
        __builtin_amdgcn_sched_barrier(0);                                    \
        if (DOX) PJ_XLOAD(RLOAD, (IT) + 2);                                   \
        __builtin_amdgcn_sched_barrier(0);                                    \
        const char* ab = (const char*)abuf + (PAR) * 16384;                   \
        const char* bb = (const char*)bbuf + (PAR) * 24576;                   \
        _Pragma("unroll")                                                     \
        for (int kk = 0; kk < 2; kk++) {                                      \
            v8s af[4], bf[3];                                                 \
            _Pragma("unroll")                                                 \
            for (int m = 0; m < 4; m++) {                                     \
                int row = wr * 64 + m * 16 + lr;                              \
                af[m] = *(const v8s*)(ab + row * 128 +                        \
                         ((kk * 64 + lg * 16) ^ ((row & 7) << 4)));           \
            }                                                                 \
            _Pragma("unroll")                                                 \
            for (int n = 0; n < 3; n++) {                                     \
                int row = wc * 48 + n * 16 + lr;                              \
                bf[n] = *(const v8s*)(bb + row * 128 +                        \
                         ((kk * 64 + lg * 16) ^ ((row & 7) << 4)));           \
            }                                                                 \
            __builtin_amdgcn_s_setprio(1);                                    \
            _Pragma("unroll")                                                 \
            for (int m = 0; m < 4; m++)                                       \
                _Pragma("unroll")                                             \
                for (int n = 0; n < 3; n++)                                   \
                    acc[m][n] = MFMA16(af[m], bf[n], acc[m][n]);              \
            __builtin_amdgcn_s_setprio(0);                                    \
        }                                                                     \
        if (DOB) {                                                            \
            PJ_CVT_WRITE(RCVT, (PAR) ^ 1);                                    \
            if (DOX) { asm volatile("s_waitcnt vmcnt(4)" ::: "memory"); }     \
            else     { asm volatile("s_waitcnt vmcnt(0)" ::: "memory"); }     \
            asm volatile("s_waitcnt lgkmcnt(0)" ::: "memory");                \
            __builtin_amdgcn_s_barrier();                                     \
        }                                                                     \
    }

__launch_bounds__(512, 1)
__global__ void proj_kernel(const float* __restrict__ x, const ushort_t* __restrict__ WT,
                            ushort_t* __restrict__ q, ushort_t* __restrict__ kb,
                            ushort_t* __restrict__ vb) {
    __shared__ ushort_t abuf[2][8192];    // [128 m][64 k] bf16, byte ^ ((row&7)<<4)
    __shared__ ushort_t bbuf[2][12288];   // [192 n][64 k] bf16, same swizzle

    int bid = blockIdx.x;
    int xcd = bid & 7, t2 = bid >> 3;
    int nh = t2 & 1, mtl = t2 >> 1;       // (mtl,0)/(mtl,1): bids differ by 8
    int mtile = xcd * 16 + mtl;
    size_t m0 = (size_t)mtile * 128;
    int c0 = nh * 192;
    int tid = threadIdx.x, lane = tid & 63, wid = tid >> 6;   // wid 0..7
    int lg = lane >> 4, lr = lane & 15;
    int wr = wid >> 2, wc = wid & 3;      // 2 x 4 wave grid

    f32x4 acc[4][3];
    #pragma unroll
    for (int m = 0; m < 4; m++)
        #pragma unroll
        for (int n = 0; n < 3; n++) acc[m][n] = (f32x4){0.f, 0.f, 0.f, 0.f};

    // A loads (COALESCED): inst i covers rows 16wid+4i..+3; lanes 0-15 = one
    // row's 256B k-slice (16B/lane). cvt -> 8B ds_write at swizzled awb[i].
    const char* xsrc[4];
    int awb[4];
    #pragma unroll
    for (int i = 0; i < 4; i++) {
        int row = 16 * wid + 4 * i + (lane >> 4);
        xsrc[i] = (const char*)x + (m0 + row) * 8192 + (lane & 15) * 16;
        awb[i] = row * 128 + (((lane & 15) * 8) ^ ((row & 7) << 4));
    }

    // B stage: 24 segs of 1KB; wave stages segs 3wid..3wid+2 (pre-swizzled).
    const char* bsrc[3];
    #pragma unroll
    for (int i = 0; i < 3; i++) {
        int row = 8 * (3 * wid + i) + (lane >> 3);
        int col = ((lane & 7) * 16) ^ ((row & 7) << 4);
        bsrc[i] = (const char*)WT + (size_t)(c0 + row) * 4096 + col;
    }

    f32x4 xs0[4], xs1[4];
    // ---- prologue: B(0)->buf0, x(0)->xs0, x(1)->xs1, cvt A(0)->abuf0 ----
    #pragma unroll
    for (int i = 0; i < 3; i++)
        gld16(bsrc[i], (char*)bbuf + (wid * 3 + i) * 1024);
    PJ_XLOAD(xs0, 0);
    PJ_XLOAD(xs1, 1);
    PJ_CVT_WRITE(xs0, 0);
    asm volatile("s_waitcnt vmcnt(0)" ::: "memory");
    asm volatile("s_waitcnt lgkmcnt(0)" ::: "memory");
    __builtin_amdgcn_s_barrier();

    // steady state: step it reads buf[it&1]; x(n) lives in xs[n&1]
    for (int it = 0; it < 30; it += 2) {
        PJ_STEP(0, it,     xs0, xs1, 1, 1);
        PJ_STEP(1, it + 1, xs1, xs0, 1, 1);
    }
    PJ_STEP(0, 30, xs0, xs1, 0, 1);   // B(31)->buf1, cvt x(31)=xs1, vmcnt(0)
    PJ_STEP(1, 31, xs1, xs0, 0, 0);   // compute only

    // epilogue: D-frag lane holds row = 4*lg+e, col = lr within each 16x16 tile
    #pragma unroll
    for (int m = 0; m < 4; m++) {
        #pragma unroll
        for (int e = 0; e < 4; e++) {
            size_t row = m0 + (size_t)(wr * 64 + m * 16 + 4 * lg + e);
            int t = (int)(row & 4095);
            size_t base = (row >> 12) * 524288;
            #pragma unroll
            for (int n = 0; n < 3; n++) {
                int col = c0 + wc * 48 + n * 16 + lr;
                int w = col >> 7, d = col & 127;
                ushort_t val = f2bf(acc[m][n][e]);
                if (w == 0)
                    q[base + (size_t)(t >> 5) * 4096 + (d >> 4) * 512 + ((d >> 3) & 1) * 256 + (t & 31) * 8 + (d & 7)] = val;
                else if (w == 1)
                    kb[base + (size_t)(t >> 5) * 4096 + (d >> 4) * 512 + ((d >> 3) & 1) * 256 + (t & 31) * 8 + (d & 7)] = val;
                else
                    vb[base + (size_t)(t >> 4) * 2048 + (d >> 5) * 512 + ((t >> 3) & 1) * 256 + (d & 31) * 8 + (t & 7)] = val;
            }
        }
    }
}

// ---------------------------------------------------------------------------
// Kernel 3: causal flash attention (UNCHANGED — ~17-19 µs, ~900 TF effective).
// 32x32 MFMA, swapped QK^T (S^T = K·Q^T), O^T = V^T·P^T. 512 blocks x 4
// waves; waves split KV tiles mod 4, merge partials via LDS at the end.
// ---------------------------------------------------------------------------
__device__ __forceinline__ f32x16 zero16() {
    f32x16 z;
    #pragma unroll
    for (int i = 0; i < 16; i++) z[i] = 0.f;
    return z;
}

#define ATT_PVC(SV, BASE, VC, CNEXT)                                          \
    {                                                                         \
        unsigned a0 = f2bf2(SV[(BASE) + 0], SV[(BASE) + 1]);                  \
        unsigned a1 = f2bf2(SV[(BASE) + 2], SV[(BASE) + 3]);                  \
        unsigned b0 = f2bf2(SV[(BASE) + 4], SV[(BASE) + 5]);                  \
        unsigned b1 = f2bf2(SV[(BASE) + 6], SV[(BASE) + 7]);                  \
        unsigned snd0 = hi ? a0 : b0, snd1 = hi ? a1 : b1;                    \
        unsigned rcv0 = (unsigned)__shfl_xor((int)snd0, 32);                  \
        unsigned rcv1 = (unsigned)__shfl_xor((int)snd1, 32);                  \
        union { unsigned u[4]; v8s v; } pf;                                   \
        pf.u[0] = hi ? rcv0 : a0;                                             \
        pf.u[1] = hi ? rcv1 : a1;                                             \
        pf.u[2] = hi ? b0 : rcv0;                                             \
        pf.u[3] = hi ? b1 : rcv1;                                             \
        __builtin_amdgcn_s_setprio(1);                                        \
        _Pragma("unroll")                                                     \
        for (int dt = 0; dt < 4; dt++)                                        \
            accO[dt] = MFMA32(VC[dt], pf.v, accO[dt]);                        \
        __builtin_amdgcn_s_setprio(0);                                        \
        if ((CNEXT) >= 0) {                                                   \
            _Pragma("unroll")                                                 \
            for (int dt = 0; dt < 4; dt++)                                    \
                VC[dt] = *(const v8s*)(vg + (CNEXT) * 2048 + dt * 512);       \
        }                                                                     \
    }

__launch_bounds__(256, 2)
__global__ void attn_kernel(const ushort_t* __restrict__ q, const ushort_t* __restrict__ kb,
                            const ushort_t* __restrict__ vb, float* __restrict__ out) {
    __shared__ float obuf[4][4][16][64];   // [srcwave][dt][r][lane]  64 KB
    __shared__ float stat[2][4][64];       // m, l per wave per lane

    int bid = blockIdx.x;
    int xcd = bid & 7, rk = bid >> 3;
    int b = xcd >> 1;                       // batch pinned to XCD pair
    int g = rk * 2 + (xcd & 1);             // 0..127
    int qt = (g & 1) ? (g >> 1) : (127 - (g >> 1));   // alternate long/short
    int qt0 = qt * 32;
    int tid = threadIdx.x, lane = tid & 63, wid = tid >> 6;
    int hi = lane >> 5, lo = lane & 31;
    size_t bb = (size_t)b * 524288;
    int nt = (qt >> 1) + 1;
    const float cexp = 0.08838834764831845f * 1.4426950408889634f;  // scale*log2e

    // Q fragments (B-operand): lane holds Q[qt0+lo][ks*16+hi*8+j]
    v8s qf[8];
    {
        const ushort_t* qg = q + bb + (size_t)qt * 4096 + (size_t)lane * 8;
        #pragma unroll
        for (int ks = 0; ks < 8; ks++) qf[ks] = *(const v8s*)(qg + ks * 512);
    }

    f32x16 accO[4];
    #pragma unroll
    for (int dt = 0; dt < 4; dt++) accO[dt] = zero16();
    float mrun = -1e30f, lrun = 0.f;

    for (int t = wid; t < nt; t += 4) {
        const ushort_t* kg = kb + bb + (size_t)t * 8192 + (size_t)lane * 8;
        const ushort_t* vg = vb + bb + (size_t)t * 8192 + (size_t)lane * 8;

        // S^T = K·Q^T : two 32-kv subtiles, K-loop over d (8 steps of 16)
        f32x16 s0 = zero16(), s1 = zero16();
        __builtin_amdgcn_s_setprio(1);
        #pragma unroll
        for (int ks = 0; ks < 8; ks++) {
            v8s kf = *(const v8s*)(kg + ks * 512);
            s0 = MFMA32(kf, qf[ks], s0);
        }
        #pragma unroll
        for (int ks = 0; ks < 8; ks++) {
            v8s kf = *(const v8s*)(kg + 4096 + ks * 512);
            s1 = MFMA32(kf, qf[ks], s1);
        }
        __builtin_amdgcn_s_setprio(0);

        // V-frag rolling pair: c=0 and c=1 issued here, latency hidden by
        // the mask + softmax VALU below.
        v8s vA[4], vB[4];
        #pragma unroll
        for (int dt = 0; dt < 4; dt++) vA[dt] = *(const v8s*)(vg + dt * 512);
        #pragma unroll
        for (int dt = 0; dt < 4; dt++) vB[dt] = *(const v8s*)(vg + 2048 + dt * 512);

        // causal mask (diagonal tile only); S^T row index kv=(r&3)+8*(r>>2)+4*hi
        if (t == nt - 1) {
            int qrow = qt0 + lo;
            #pragma unroll
            for (int r = 0; r < 16; r++) {
                int kvb = t * 64 + (r & 3) + 8 * (r >> 2) + 4 * hi;
                if (kvb > qrow) s0[r] = -1e30f;
                if (kvb + 32 > qrow) s1[r] = -1e30f;
            }
        }

        // online softmax: lane owns q-row lo; only cross-lane op is xor-32
        float mx = s0[0];
        #pragma unroll
        for (int r = 1; r < 16; r++) mx = fmaxf(mx, s0[r]);
        #pragma unroll
        for (int r = 0; r < 16; r++) mx = fmaxf(mx, s1[r]);
        mx = fmaxf(mx, __shfl_xor(mx, 32));

        if (__any(mx > mrun + 62.7f)) {     // defer-max: skip rescale if growth < 8/cexp
            float mnew = fmaxf(mrun, mx);
            float fr = exp2f((mrun - mnew) * cexp);
            lrun *= fr;
            #pragma unroll
            for (int dt = 0; dt < 4; dt++)
                #pragma unroll
                for (int r = 0; r < 16; r++) accO[dt][r] *= fr;
            mrun = mnew;
        }
        float mc = mrun * cexp;
        float rs = 0.f;
        #pragma unroll
        for (int r = 0; r < 16; r++) { s0[r] = exp2f(fmaf(s0[r], cexp, -mc)); rs += s0[r]; }
        #pragma unroll
        for (int r = 0; r < 16; r++) { s1[r] = exp2f(fmaf(s1[r], cexp, -mc)); rs += s1[r]; }
        rs += __shfl_xor(rs, 32);
        lrun += rs;

        // PV: O^T += V^T·P^T ; P-frag assembled in-loop (1 shfl pair / chunk),
        // V-frags prefetched 2 chunks ahead into the just-consumed set.
        ATT_PVC(s0, 0, vA, 2);
        ATT_PVC(s0, 8, vB, 3);
        ATT_PVC(s1, 0, vA, -1);
        ATT_PVC(s1, 8, vB, -1);
    }

    // ---- merge the 4 waves' partial (m, l, O^T) states ----
    #pragma unroll
    for (int dt = 0; dt < 4; dt++)
        #pragma unroll
        for (int r = 0; r < 16; r++)
            obuf[wid][dt][r][lane] = accO[dt][r];
    stat[0][wid][lane] = mrun;
    stat[1][wid][lane] = lrun;
    __syncthreads();

    float m0 = stat[0][0][lane], m1 = stat[0][1][lane];
    float m2 = stat[0][2][lane], m3 = stat[0][3][lane];
    float m = fmaxf(fmaxf(m0, m1), fmaxf(m2, m3));
    float f0 = exp2f((m0 - m) * cexp), f1 = exp2f((m1 - m) * cexp);
    float f2 = exp2f((m2 - m) * cexp), f3 = exp2f((m3 - m) * cexp);
    float lsum = f0 * stat[1][0][lane] + f1 * stat[1][1][lane]
               + f2 * stat[1][2][lane] + f3 * stat[1][3][lane];
    float linv = 1.0f / lsum;

    float o[16];
    #pragma unroll
    for (int r = 0; r < 16; r++)
        o[r] = (f0 * obuf[0][wid][r][lane] + f1 * obuf[1][wid][r][lane]
              + f2 * obuf[2][wid][r][lane] + f3 * obuf[3][wid][r][lane]) * linv;

    // wave wid owns output cols wid*32..+32; col = wid*32 + 8a + 4hi + e
    float* orow = out + ((size_t)b * 4096 + qt0 + lo) * 128 + wid * 32 + 4 * hi;
    #pragma unroll
    for (int a = 0; a < 4; a++) {
        float4 vv;
        vv.x = o[4 * a + 0]; vv.y = o[4 * a + 1];
        vv.z = o[4 * a + 2]; vv.w = o[4 * a + 3];
        *(float4*)(orow + 8 * a) = vv;
    }
}

// ---------------------------------------------------------------------------
extern "C" void kernel_launch(void* const* d_in, const int* in_sizes, int n_in,
                              void* d_out, int out_size, void* d_ws, size_t ws_size,
                              hipStream_t stream) {
    const float* x  = (const float*)d_in[0];
    const float* Wq = (const float*)d_in[1];
    const float* Wk = (const float*)d_in[2];
    const float* Wv = (const float*)d_in[3];
    float* out = (float*)d_out;
    char* ws = (char*)d_ws;

    ushort_t* q  = (ushort_t*)(ws);               // 4 MB  q_blk
    ushort_t* kb = (ushort_t*)(ws + (4u << 20));  // 4 MB  k_blk
    ushort_t* vb = (ushort_t*)(ws + (8u << 20));  // 4 MB  v_blk
    ushort_t* WT = (ushort_t*)(ws + (12u << 20)); // 1.5MB WT bf16 [384][2048]

    transpose_w<<<dim3(96), dim3(256), 0, stream>>>(Wq, Wk, Wv, WT);
    proj_kernel<<<dim3(256), dim3(512), 0, stream>>>(x, WT, q, kb, vb);
    attn_kernel<<<dim3(512), dim3(256), 0, stream>>>(q, kb, vb, out);
}

// Round 13
// 91.829 us; speedup vs baseline: 1.1087x; 1.1087x over previous
//
#include <hip/hip_runtime.h>
#include <hip/hip_bf16.h>
#include <stdint.h>

typedef unsigned short ushort_t;
typedef short v8s __attribute__((ext_vector_type(8)));
typedef float f32x4 __attribute__((ext_vector_type(4)));
typedef float f32x16 __attribute__((ext_vector_type(16)));

#define MFMA16(a, b, c) __builtin_amdgcn_mfma_f32_16x16x32_bf16(a, b, c, 0, 0, 0)
#define MFMA32(a, b, c) __builtin_amdgcn_mfma_f32_32x32x16_bf16(a, b, c, 0, 0, 0)

typedef __attribute__((address_space(1))) void gvoid;
typedef __attribute__((address_space(3))) void svoid;

__device__ __forceinline__ void gld16(const void* g, void* s) {
    __builtin_amdgcn_global_load_lds((gvoid*)g, (svoid*)s, 16, 0, 0);
}

__device__ __forceinline__ ushort_t f2bf(float f) {
    union { __hip_bfloat16 b; ushort_t u; } c;
    c.b = __float2bfloat16(f);
    return c.u;
}

__device__ __forceinline__ unsigned f2bf2(float a, float b) {
    union { __hip_bfloat162 b2; unsigned u; } c;
    c.b2 = __float22bfloat162_rn(make_float2(a, b));
    return c.u;
}

// ---------------------------------------------------------------------------
// Kernel 1: transpose W [2048][128] f32 -> WT [384][2048] bf16 (q|k|v rows)
// ---------------------------------------------------------------------------
__global__ void transpose_w(const float* __restrict__ Wq, const float* __restrict__ Wk,
                            const float* __restrict__ Wv, ushort_t* __restrict__ WT) {
    __shared__ float tile[64][132];
    int bid = blockIdx.x;            // 96 = 3 weights x 32 k-blocks
    int w = bid >> 5;
    int k0 = (bid & 31) << 6;
    const float* W = (w == 0) ? Wq : ((w == 1) ? Wk : Wv);
    int tid = threadIdx.x;
    #pragma unroll
    for (int i = 0; i < 8; i++) {
        int row = i * 8 + (tid >> 5);
        int col = (tid & 31) * 4;
        float4 v = *(const float4*)(W + (size_t)(k0 + row) * 128 + col);
        tile[row][col] = v.x; tile[row][col + 1] = v.y;
        tile[row][col + 2] = v.z; tile[row][col + 3] = v.w;
    }
    __syncthreads();
    int n = tid >> 1, kh = (tid & 1) * 32;
    ushort_t* dst = WT + ((size_t)(w * 128 + n)) * 2048 + k0 + kh;
    #pragma unroll
    for (int j = 0; j < 32; j += 4) {
        union { ushort_t u[4]; uint2 v2; } pk;
        #pragma unroll
        for (int e = 0; e < 4; e++) pk.u[e] = f2bf(tile[kh + j + e][n]);
        *(uint2*)(dst + j) = pk.v2;
    }
}

// ---------------------------------------------------------------------------
// Kernel 2: fused QKV projection v13 — R12 geometry + m201 phase schedule.
// 128m x 192n tile, BK=64, 32 K-tiles; grid 256 = 128 mt x 2 nh (XCD-paired);
// 512 threads = 8 waves (2wr x 4wc), wave = 64m x 48n, acc[4][3].
// Per K-tile: 2 phases x {ds_read frags || staging issue -> s_barrier ->
// lgkmcnt(0) -> sched_barrier -> setprio(1) 12 MFMA setprio(0) -> s_barrier}.
// vmcnt(4) once per tile (P2): B(t+1) drained, x(t+2) stays in flight.
// A: coalesced f32 x loads 2-ahead -> cvt_pk -> 8B swizzled ds_write.
// B: gld16 1-ahead, pre-swizzled source. LDS 80 KB dbuf. NO __syncthreads
// in the loop — raw barriers only (no compiler vmcnt(0) drain).
// Blocked output layouts (per batch 524288 elems):
//   q_blk/k_blk: (t>>5)*4096 + (d>>4)*512 + ((d>>3)&1)*256 + (t&31)*8 + (d&7)
//   v_blk:       (t>>4)*2048 + (d>>5)*512 + ((t>>3)&1)*256 + (d&31)*8 + (t&7)
// ---------------------------------------------------------------------------
#define PJ_XLOAD(S, IT)                                                       \
    {                                                                         \
        _Pragma("unroll")                                                     \
        for (int i = 0; i < 4; i++)                                           \
            S[i] = *(const f32x4*)(xsrc[i] + (size_t)(IT) * 256);             \
    }

#define PJ_CVT_WRITE(RS, PAR)                                                 \
    {                                                                         \
        _Pragma("unroll")                                                     \
        for (int i = 0; i < 4; i++) {                                         \
            uint2 p;                                                          \
            p.x = f2bf2(RS[i][0], RS[i][1]);                                  \
            p.y = f2bf2(RS[i][2], RS[i][3]);                                  \
            *(uint2*)((char*)abuf + (PAR) * 16384 + awb[i]) = p;              \
        }                                                                     \
    }

// Phase 1 of tile IT (kk=0): frag reads + B(t+1) issue, barrier, MFMA.
#define PJ_PHASE1(PAR, IT, DOB)                                               \
    {                                                                         \
        const char* ab = (const char*)abuf + (PAR) * 16384;                   \
        const char* bb = (const char*)bbuf + (PAR) * 24576;                   \
        v8s af[4], bf[3];                                                     \
        _Pragma("unroll")                                                     \
        for (int m = 0; m < 4; m++) {                                         \
            int row = wr * 64 + m * 16 + lr;                                  \
            af[m] = *(const v8s*)(ab + row * 128 + ((lg * 16) ^ ((row & 7) << 4))); \
        }                                                                     \
        _Pragma("unroll")                                                     \
        for (int n = 0; n < 3; n++) {                                         \
            int row = wc * 48 + n * 16 + lr;                                  \
            bf[n] = *(const v8s*)(bb + row * 128 + ((lg * 16) ^ ((row & 7) << 4))); \
        }                                                                     \
        __builtin_amdgcn_sched_barrier(0);                                    \
        if (DOB) {                                                            \
            _Pragma("unroll")                                                 \
            for (int i = 0; i < 3; i++)                                       \
                gld16(bsrc[i] + (size_t)((IT) + 1) * 128,                     \
                      (char*)bbuf + ((PAR) ^ 1) * 24576 + (wid * 3 + i) * 1024); \
        }                                                                     \
        __builtin_amdgcn_sched_barrier(0);                                    \
        __builtin_amdgcn_s_barrier();                                         \
        asm volatile("s_waitcnt lgkmcnt(0)" ::: "memory");                    \
        __builtin_amdgcn_sched_barrier(0);                                    \
        __builtin_amdgcn_s_setprio(1);                                        \
        _Pragma("unroll")                                                     \
        for (int m = 0; m < 4; m++)                                           \
            _Pragma("unroll")                                                 \
            for (int n = 0; n < 3; n++)                                       \
                acc[m][n] = MFMA16(af[m], bf[n], acc[m][n]);                  \
        __builtin_amdgcn_s_setprio(0);                                        \
        __builtin_amdgcn_s_barrier();                                         \
    }

// Phase 2 of tile IT (kk=1): frag reads + x(t+2) issue + cvt/ds_write A(t+1)
// + counted vmcnt, barrier, MFMA.
#define PJ_PHASE2(PAR, IT, RLOAD, RCVT, DOX, DOB)                             \
    {                                                                         \
        const char* ab = (const char*)abuf + (PAR) * 16384;                   \
        const char* bb = (const char*)bbuf + (PAR) * 24576;                   \
        v8s af[4], bf[3];                                                     \
        _Pragma("unroll")                                                     \
        for (int m = 0; m < 4; m++) {                                         \
            int row = wr * 64 + m * 16 + lr;                                  \
            af[m] = *(const v8s*)(ab + row * 128 + ((64 + lg * 16) ^ ((row & 7) << 4))); \
        }                                                                     \
        _Pragma("unroll")                                                     \
        for (int n = 0; n < 3; n++) {                                         \
            int row = wc * 48 + n * 16 + lr;                                  \
            bf[n] = *(const v8s*)(bb + row * 128 + ((64 + lg * 16) ^ ((row & 7) << 4))); \
        }                                                                     \
        __builtin_amdgcn_sched_barrier(0);                                    \
        if (DOX) PJ_XLOAD(RLOAD, (IT) + 2);                                   \
        __builtin_amdgcn_sched_barrier(0);                                    \
        if (DOB) PJ_CVT_WRITE(RCVT, (PAR) ^ 1);                               \
        __builtin_amdgcn_sched_barrier(0);                                    \
        if (DOB) {                                                            \
            if (DOX) { asm volatile("s_waitcnt vmcnt(4)" ::: "memory"); }     \
            else     { asm volatile("s_waitcnt vmcnt(0)" ::: "memory"); }     \
        }                                                                     \
        __builtin_amdgcn_s_barrier();                                         \
        asm volatile("s_waitcnt lgkmcnt(0)" ::: "memory");                    \
        __builtin_amdgcn_sched_barrier(0);                                    \
        __builtin_amdgcn_s_setprio(1);                                        \
        _Pragma("unroll")                                                     \
        for (int m = 0; m < 4; m++)                                           \
            _Pragma("unroll")                                                 \
            for (int n = 0; n < 3; n++)                                       \
                acc[m][n] = MFMA16(af[m], bf[n], acc[m][n]);                  \
        __builtin_amdgcn_s_setprio(0);                                        \
        __builtin_amdgcn_s_barrier();                                         \
    }

#define PJ_TILE(PAR, IT, RLOAD, RCVT, DOX, DOB)                               \
    PJ_PHASE1(PAR, IT, DOB)                                                   \
    PJ_PHASE2(PAR, IT, RLOAD, RCVT, DOX, DOB)

__launch_bounds__(512, 1)
__global__ void proj_kernel(const float* __restrict__ x, const ushort_t* __restrict__ WT,
                            ushort_t* __restrict__ q, ushort_t* __restrict__ kb,
                            ushort_t* __restrict__ vb) {
    __shared__ ushort_t abuf[2][8192];    // [128 m][64 k] bf16, byte ^ ((row&7)<<4)
    __shared__ ushort_t bbuf[2][12288];   // [192 n][64 k] bf16, same swizzle

    int bid = blockIdx.x;
    int xcd = bid & 7, t2 = bid >> 3;
    int nh = t2 & 1, mtl = t2 >> 1;       // (mtl,0)/(mtl,1): bids differ by 8
    int mtile = xcd * 16 + mtl;
    size_t m0 = (size_t)mtile * 128;
    int c0 = nh * 192;
    int tid = threadIdx.x, lane = tid & 63, wid = tid >> 6;   // wid 0..7
    int lg = lane >> 4, lr = lane & 15;
    int wr = wid >> 2, wc = wid & 3;      // 2 x 4 wave grid

    f32x4 acc[4][3];
    #pragma unroll
    for (int m = 0; m < 4; m++)
        #pragma unroll
        for (int n = 0; n < 3; n++) acc[m][n] = (f32x4){0.f, 0.f, 0.f, 0.f};

    // A loads (COALESCED): inst i covers rows 16wid+4i..+3; lanes 0-15 = one
    // row's 256B k-slice (16B/lane). cvt -> 8B ds_write at swizzled awb[i].
    const char* xsrc[4];
    int awb[4];
    #pragma unroll
    for (int i = 0; i < 4; i++) {
        int row = 16 * wid + 4 * i + (lane >> 4);
        xsrc[i] = (const char*)x + (m0 + row) * 8192 + (lane & 15) * 16;
        awb[i] = row * 128 + (((lane & 15) * 8) ^ ((row & 7) << 4));
    }

    // B stage: 24 segs of 1KB; wave stages segs 3wid..3wid+2 (pre-swizzled).
    const char* bsrc[3];
    #pragma unroll
    for (int i = 0; i < 3; i++) {
        int row = 8 * (3 * wid + i) + (lane >> 3);
        int col = ((lane & 7) * 16) ^ ((row & 7) << 4);
        bsrc[i] = (const char*)WT + (size_t)(c0 + row) * 4096 + col;
    }

    f32x4 xs0[4], xs1[4];
    // ---- prologue: B(0)->buf0, x(0)->xs0, x(1)->xs1, cvt A(0)->abuf0 ----
    #pragma unroll
    for (int i = 0; i < 3; i++)
        gld16(bsrc[i], (char*)bbuf + (wid * 3 + i) * 1024);
    PJ_XLOAD(xs0, 0);
    PJ_XLOAD(xs1, 1);
    PJ_CVT_WRITE(xs0, 0);
    asm volatile("s_waitcnt vmcnt(0)" ::: "memory");
    asm volatile("s_waitcnt lgkmcnt(0)" ::: "memory");
    __builtin_amdgcn_s_barrier();

    // steady state: tile t reads buf[t&1]; x(n) lives in xs[n&1]
    for (int t = 0; t < 30; t += 2) {
        PJ_TILE(0, t,     xs0, xs1, 1, 1);
        PJ_TILE(1, t + 1, xs1, xs0, 1, 1);
    }
    PJ_TILE(0, 30, xs0, xs1, 0, 1);   // B(31)->buf1, cvt x(31)=xs1, vmcnt(0)
    PJ_TILE(1, 31, xs1, xs0, 0, 0);   // compute only

    // epilogue: D-frag lane holds row = 4*lg+e, col = lr within each 16x16 tile
    #pragma unroll
    for (int m = 0; m < 4; m++) {
        #pragma unroll
        for (int e = 0; e < 4; e++) {
            size_t row = m0 + (size_t)(wr * 64 + m * 16 + 4 * lg + e);
            int t = (int)(row & 4095);
            size_t base = (row >> 12) * 524288;
            #pragma unroll
            for (int n = 0; n < 3; n++) {
                int col = c0 + wc * 48 + n * 16 + lr;
                int w = col >> 7, d = col & 127;
                ushort_t val = f2bf(acc[m][n][e]);
                if (w == 0)
                    q[base + (size_t)(t >> 5) * 4096 + (d >> 4) * 512 + ((d >> 3) & 1) * 256 + (t & 31) * 8 + (d & 7)] = val;
                else if (w == 1)
                    kb[base + (size_t)(t >> 5) * 4096 + (d >> 4) * 512 + ((d >> 3) & 1) * 256 + (t & 31) * 8 + (d & 7)] = val;
                else
                    vb[base + (size_t)(t >> 4) * 2048 + (d >> 5) * 512 + ((t >> 3) & 1) * 256 + (d & 31) * 8 + (t & 7)] = val;
            }
        }
    }
}

// ---------------------------------------------------------------------------
// Kernel 3: causal flash attention (UNCHANGED — ~17-19 µs, ~900 TF effective).
// 32x32 MFMA, swapped QK^T (S^T = K·Q^T), O^T = V^T·P^T. 512 blocks x 4
// waves; waves split KV tiles mod 4, merge partials via LDS at the end.
// ---------------------------------------------------------------------------
__device__ __forceinline__ f32x16 zero16() {
    f32x16 z;
    #pragma unroll
    for (int i = 0; i < 16; i++) z[i] = 0.f;
    return z;
}

#define ATT_PVC(SV, BASE, VC, CNEXT)                                          \
    {                                                                         \
        unsigned a0 = f2bf2(SV[(BASE) + 0], SV[(BASE) + 1]);                  \
        unsigned a1 = f2bf2(SV[(BASE) + 2], SV[(BASE) + 3]);                  \
        unsigned b0 = f2bf2(SV[(BASE) + 4], SV[(BASE) + 5]);                  \
        unsigned b1 = f2bf2(SV[(BASE) + 6], SV[(BASE) + 7]);                  \
        unsigned snd0 = hi ? a0 : b0, snd1 = hi ? a1 : b1;                    \
        unsigned rcv0 = (unsigned)__shfl_xor((int)snd0, 32);                  \
        unsigned rcv1 = (unsigned)__shfl_xor((int)snd1, 32);                  \
        union { unsigned u[4]; v8s v; } pf;                                   \
        pf.u[0] = hi ? rcv0 : a0;                                             \
        pf.u[1] = hi ? rcv1 : a1;                                             \
        pf.u[2] = hi ? b0 : rcv0;                                             \
        pf.u[3] = hi ? b1 : rcv1;                                             \
        __builtin_amdgcn_s_setprio(1);                                        \
        _Pragma("unroll")                                                     \
        for (int dt = 0; dt < 4; dt++)                                        \
            accO[dt] = MFMA32(VC[dt], pf.v, accO[dt]);                        \
        __builtin_amdgcn_s_setprio(0);                                        \
        if ((CNEXT) >= 0) {                                                   \
            _Pragma("unroll")                                                 \
            for (int dt = 0; dt < 4; dt++)                                    \
                VC[dt] = *(const v8s*)(vg + (CNEXT) * 2048 + dt * 512);       \
        }                                                                     \
    }

__launch_bounds__(256, 2)
__global__ void attn_kernel(const ushort_t* __restrict__ q, const ushort_t* __restrict__ kb,
                            const ushort_t* __restrict__ vb, float* __restrict__ out) {
    __shared__ float obuf[4][4][16][64];   // [srcwave][dt][r][lane]  64 KB
    __shared__ float stat[2][4][64];       // m, l per wave per lane

    int bid = blockIdx.x;
    int xcd = bid & 7, rk = bid >> 3;
    int b = xcd >> 1;                       // batch pinned to XCD pair
    int g = rk * 2 + (xcd & 1);             // 0..127
    int qt = (g & 1) ? (g >> 1) : (127 - (g >> 1));   // alternate long/short
    int qt0 = qt * 32;
    int tid = threadIdx.x, lane = tid & 63, wid = tid >> 6;
    int hi = lane >> 5, lo = lane & 31;
    size_t bb = (size_t)b * 524288;
    int nt = (qt >> 1) + 1;
    const float cexp = 0.08838834764831845f * 1.4426950408889634f;  // scale*log2e

    // Q fragments (B-operand): lane holds Q[qt0+lo][ks*16+hi*8+j]
    v8s qf[8];
    {
        const ushort_t* qg = q + bb + (size_t)qt * 4096 + (size_t)lane * 8;
        #pragma unroll
        for (int ks = 0; ks < 8; ks++) qf[ks] = *(const v8s*)(qg + ks * 512);
    }

    f32x16 accO[4];
    #pragma unroll
    for (int dt = 0; dt < 4; dt++) accO[dt] = zero16();
    float mrun = -1e30f, lrun = 0.f;

    for (int t = wid; t < nt; t += 4) {
        const ushort_t* kg = kb + bb + (size_t)t * 8192 + (size_t)lane * 8;
        const ushort_t* vg = vb + bb + (size_t)t * 8192 + (size_t)lane * 8;

        // S^T = K·Q^T : two 32-kv subtiles, K-loop over d (8 steps of 16)
        f32x16 s0 = zero16(), s1 = zero16();
        __builtin_amdgcn_s_setprio(1);
        #pragma unroll
        for (int ks = 0; ks < 8; ks++) {
            v8s kf = *(const v8s*)(kg + ks * 512);
            s0 = MFMA32(kf, qf[ks], s0);
        }
        #pragma unroll
        for (int ks = 0; ks < 8; ks++) {
            v8s kf = *(const v8s*)(kg + 4096 + ks * 512);
            s1 = MFMA32(kf, qf[ks], s1);
        }
        __builtin_amdgcn_s_setprio(0);

        // V-frag rolling pair: c=0 and c=1 issued here, latency hidden by
        // the mask + softmax VALU below.
        v8s vA[4], vB[4];
        #pragma unroll
        for (int dt = 0; dt < 4; dt++) vA[dt] = *(const v8s*)(vg + dt * 512);
        #pragma unroll
        for (int dt = 0; dt < 4; dt++) vB[dt] = *(const v8s*)(vg + 2048 + dt * 512);

        // causal mask (diagonal tile only); S^T row index kv=(r&3)+8*(r>>2)+4*hi
        if (t == nt - 1) {
            int qrow = qt0 + lo;
            #pragma unroll
            for (int r = 0; r < 16; r++) {
                int kvb = t * 64 + (r & 3) + 8 * (r >> 2) + 4 * hi;
                if (kvb > qrow) s0[r] = -1e30f;
                if (kvb + 32 > qrow) s1[r] = -1e30f;
            }
        }

        // online softmax: lane owns q-row lo; only cross-lane op is xor-32
        float mx = s0[0];
        #pragma unroll
        for (int r = 1; r < 16; r++) mx = fmaxf(mx, s0[r]);
        #pragma unroll
        for (int r = 0; r < 16; r++) mx = fmaxf(mx, s1[r]);
        mx = fmaxf(mx, __shfl_xor(mx, 32));

        if (__any(mx > mrun + 62.7f)) {     // defer-max: skip rescale if growth < 8/cexp
            float mnew = fmaxf(mrun, mx);
            float fr = exp2f((mrun - mnew) * cexp);
            lrun *= fr;
            #pragma unroll
            for (int dt = 0; dt < 4; dt++)
                #pragma unroll
                for (int r = 0; r < 16; r++) accO[dt][r] *= fr;
            mrun = mnew;
        }
        float mc = mrun * cexp;
        float rs = 0.f;
        #pragma unroll
        for (int r = 0; r < 16; r++) { s0[r] = exp2f(fmaf(s0[r], cexp, -mc)); rs += s0[r]; }
        #pragma unroll
        for (int r = 0; r < 16; r++) { s1[r] = exp2f(fmaf(s1[r], cexp, -mc)); rs += s1[r]; }
        rs += __shfl_xor(rs, 32);
        lrun += rs;

        // PV: O^T += V^T·P^T ; P-frag assembled in-loop (1 shfl pair / chunk),
        // V-frags prefetched 2 chunks ahead into the just-consumed set.
        ATT_PVC(s0, 0, vA, 2);
        ATT_PVC(s0, 8, vB, 3);
        ATT_PVC(s1, 0, vA, -1);
        ATT_PVC(s1, 8, vB, -1);
    }

    // ---- merge the 4 waves' partial (m, l, O^T) states ----
    #pragma unroll
    for (int dt = 0; dt < 4; dt++)
        #pragma unroll
        for (int r = 0; r < 16; r++)
            obuf[wid][dt][r][lane] = accO[dt][r];
    stat[0][wid][lane] = mrun;
    stat[1][wid][lane] = lrun;
    __syncthreads();

    float m0 = stat[0][0][lane], m1 = stat[0][1][lane];
    float m2 = stat[0][2][lane], m3 = stat[0][3][lane];
    float m = fmaxf(fmaxf(m0, m1), fmaxf(m2, m3));
    float f0 = exp2f((m0 - m) * cexp), f1 = exp2f((m1 - m) * cexp);
    float f2 = exp2f((m2 - m) * cexp), f3 = exp2f((m3 - m) * cexp);
    float lsum = f0 * stat[1][0][lane] + f1 * stat[1][1][lane]
               + f2 * stat[1][2][lane] + f3 * stat[1][3][lane];
    float linv = 1.0f / lsum;

    float o[16];
    #pragma unroll
    for (int r = 0; r < 16; r++)
        o[r] = (f0 * obuf[0][wid][r][lane] + f1 * obuf[1][wid][r][lane]
              + f2 * obuf[2][wid][r][lane] + f3 * obuf[3][wid][r][lane]) * linv;

    // wave wid owns output cols wid*32..+32; col = wid*32 + 8a + 4hi + e
    float* orow = out + ((size_t)b * 4096 + qt0 + lo) * 128 + wid * 32 + 4 * hi;
    #pragma unroll
    for (int a = 0; a < 4; a++) {
        float4 vv;
        vv.x = o[4 * a + 0]; vv.y = o[4 * a + 1];
        vv.z = o[4 * a + 2]; vv.w = o[4 * a + 3];
        *(float4*)(orow + 8 * a) = vv;
    }
}

// ---------------------------------------------------------------------------
extern "C" void kernel_launch(void* const* d_in, const int* in_sizes, int n_in,
                              void* d_out, int out_size, void* d_ws, size_t ws_size,
                              hipStream_t stream) {
    const float* x  = (const float*)d_in[0];
    const float* Wq = (const float*)d_in[1];
    const float* Wk = (const float*)d_in[2];
    const float* Wv = (const float*)d_in[3];
    float* out = (float*)d_out;
    char* ws = (char*)d_ws;

    ushort_t* q  = (ushort_t*)(ws);               // 4 MB  q_blk
    ushort_t* kb = (ushort_t*)(ws + (4u << 20));  // 4 MB  k_blk
    ushort_t* vb = (ushort_t*)(ws + (8u << 20));  // 4 MB  v_blk
    ushort_t* WT = (ushort_t*)(ws + (12u << 20)); // 1.5MB WT bf16 [384][2048]

    transpose_w<<<dim3(96), dim3(256), 0, stream>>>(Wq, Wk, Wv, WT);
    proj_kernel<<<dim3(256), dim3(512), 0, stream>>>(x, WT, q, kb, vb);
    attn_kernel<<<dim3(512), dim3(256), 0, stream>>>(q, kb, vb, out);
}

// Round 14
// 91.696 us; speedup vs baseline: 1.1103x; 1.0014x over previous
//
#include <hip/hip_runtime.h>
#include <hip/hip_bf16.h>
#include <stdint.h>

typedef unsigned short ushort_t;
typedef short v8s __attribute__((ext_vector_type(8)));
typedef float f32x4 __attribute__((ext_vector_type(4)));
typedef float f32x16 __attribute__((ext_vector_type(16)));

#define MFMA16(a, b, c) __builtin_amdgcn_mfma_f32_16x16x32_bf16(a, b, c, 0, 0, 0)
#define MFMA32(a, b, c) __builtin_amdgcn_mfma_f32_32x32x16_bf16(a, b, c, 0, 0, 0)

typedef __attribute__((address_space(1))) void gvoid;
typedef __attribute__((address_space(3))) void svoid;

__device__ __forceinline__ void gld16(const void* g, void* s) {
    __builtin_amdgcn_global_load_lds((gvoid*)g, (svoid*)s, 16, 0, 0);
}

__device__ __forceinline__ ushort_t f2bf(float f) {
    union { __hip_bfloat16 b; ushort_t u; } c;
    c.b = __float2bfloat16(f);
    return c.u;
}

__device__ __forceinline__ unsigned f2bf2(float a, float b) {
    union { __hip_bfloat162 b2; unsigned u; } c;
    c.b2 = __float22bfloat162_rn(make_float2(a, b));
    return c.u;
}

// ---------------------------------------------------------------------------
// Kernel 1: transpose W [2048][128] f32 -> WT [384][2048] bf16 (q|k|v rows)
// ---------------------------------------------------------------------------
__global__ void transpose_w(const float* __restrict__ Wq, const float* __restrict__ Wk,
                            const float* __restrict__ Wv, ushort_t* __restrict__ WT) {
    __shared__ float tile[64][132];
    int bid = blockIdx.x;            // 96 = 3 weights x 32 k-blocks
    int w = bid >> 5;
    int k0 = (bid & 31) << 6;
    const float* W = (w == 0) ? Wq : ((w == 1) ? Wk : Wv);
    int tid = threadIdx.x;
    #pragma unroll
    for (int i = 0; i < 8; i++) {
        int row = i * 8 + (tid >> 5);
        int col = (tid & 31) * 4;
        float4 v = *(const float4*)(W + (size_t)(k0 + row) * 128 + col);
        tile[row][col] = v.x; tile[row][col + 1] = v.y;
        tile[row][col + 2] = v.z; tile[row][col + 3] = v.w;
    }
    __syncthreads();
    int n = tid >> 1, kh = (tid & 1) * 32;
    ushort_t* dst = WT + ((size_t)(w * 128 + n)) * 2048 + k0 + kh;
    #pragma unroll
    for (int j = 0; j < 32; j += 4) {
        union { ushort_t u[4]; uint2 v2; } pk;
        #pragma unroll
        for (int e = 0; e < 4; e++) pk.u[e] = f2bf(tile[kh + j + e][n]);
        *(uint2*)(dst + j) = pk.v2;
    }
}

// ---------------------------------------------------------------------------
// Kernel 2: fused QKV projection v14 — v13 + 2-tiles-ahead B pipeline.
// 128m x 192n tile, BK=64, 32 K-tiles; grid 256 = 128 mt x 2 nh (XCD-paired);
// 512 threads = 8 waves (2wr x 4wc), wave = 64m x 48n, acc[4][3].
// bbuf has THREE rotating slots (B issued at P1(t) for tile t+2); abuf 2
// slots. Steady-state wait: vmcnt(7) at P2(t) = leave {B(t+2)3, x(t+2)4}
// in flight across both barriers; drains exactly {B(t+1), x(t+1)}.
// Unrolled x6 so A-parity (2) and B-slot (3) are compile-time constants.
// Per phase: {ds_read frags || staging issue -> s_barrier -> lgkmcnt(0) ->
// sched_barrier -> setprio(1) 12 MFMA setprio(0) -> s_barrier}.
// A: coalesced f32 x loads 2-ahead -> cvt_pk -> 8B swizzled ds_write.
// LDS 104 KB (2x16K A + 3x24K B), 1 block/CU. Raw barriers only.
// Blocked output layouts (per batch 524288 elems):
//   q_blk/k_blk: (t>>5)*4096 + (d>>4)*512 + ((d>>3)&1)*256 + (t&31)*8 + (d&7)
//   v_blk:       (t>>4)*2048 + (d>>5)*512 + ((t>>3)&1)*256 + (d&31)*8 + (t&7)
// ---------------------------------------------------------------------------
#define PJ_XLOAD(S, IT)                                                       \
    {                                                                         \
        _Pragma("unroll")                                                     \
        for (int i = 0; i < 4; i++)                                           \
            S[i] = *(const f32x4*)(xsrc[i] + (size_t)(IT) * 256);             \
    }

#define PJ_CVT_WRITE(RS, PAR)                                                 \
    {                                                                         \
        _Pragma("unroll")                                                     \
        for (int i = 0; i < 4; i++) {                                         \
            uint2 p;                                                          \
            p.x = f2bf2(RS[i][0], RS[i][1]);                                  \
            p.y = f2bf2(RS[i][2], RS[i][3]);                                  \
            *(uint2*)((char*)abuf + (PAR) * 16384 + awb[i]) = p;              \
        }                                                                     \
    }

// Phase 1 of tile IT (kk=0): frag reads + B(t+2) issue, barrier, MFMA.
#define PJ_PHASE1(APAR, BSLOT, BNSLOT, IT, DOB2)                              \
    {                                                                         \
        const char* ab = (const char*)abuf + (APAR) * 16384;                  \
        const char* bb = (const char*)bbuf + (BSLOT) * 24576;                 \
        v8s af[4], bf[3];                                                     \
        _Pragma("unroll")                                                     \
        for (int m = 0; m < 4; m++) {                                         \
            int row = wr * 64 + m * 16 + lr;                                  \
            af[m] = *(const v8s*)(ab + row * 128 + ((lg * 16) ^ ((row & 7) << 4))); \
        }                                                                     \
        _Pragma("unroll")                                                     \
        for (int n = 0; n < 3; n++) {                                         \
            int row = wc * 48 + n * 16 + lr;                                  \
            bf[n] = *(const v8s*)(bb + row * 128 + ((lg * 16) ^ ((row & 7) << 4))); \
        }                                                                     \
        __builtin_amdgcn_sched_barrier(0);                                    \
        if (DOB2) {                                                           \
            _Pragma("unroll")                                                 \
            for (int i = 0; i < 3; i++)                                       \
                gld16(bsrc[i] + (size_t)((IT) + 2) * 128,                     \
                      (char*)bbuf + (BNSLOT) * 24576 + (wid * 3 + i) * 1024); \
        }                                                                     \
        __builtin_amdgcn_sched_barrier(0);                                    \
        __builtin_amdgcn_s_barrier();                                         \
        asm volatile("s_waitcnt lgkmcnt(0)" ::: "memory");                    \
        __builtin_amdgcn_sched_barrier(0);                                    \
        __builtin_amdgcn_s_setprio(1);                                        \
        _Pragma("unroll")                                                     \
        for (int m = 0; m < 4; m++)                                           \
            _Pragma("unroll")                                                 \
            for (int n = 0; n < 3; n++)                                       \
                acc[m][n] = MFMA16(af[m], bf[n], acc[m][n]);                  \
        __builtin_amdgcn_s_setprio(0);                                        \
        __builtin_amdgcn_s_barrier();                                         \
    }

// Phase 2 of tile IT (kk=1): frag reads + x(t+2) issue + cvt/ds_write A(t+1)
// + counted vmcnt (7 steady / 0 at drain), barrier, MFMA.
#define PJ_PHASE2(APAR, BSLOT, IT, RLOAD, RCVT, DOX2, DOCVT, VMN)             \
    {                                                                         \
        const char* ab = (const char*)abuf + (APAR) * 16384;                  \
        const char* bb = (const char*)bbuf + (BSLOT) * 24576;                 \
        v8s af[4], bf[3];                                                     \
        _Pragma("unroll")                                                     \
        for (int m = 0; m < 4; m++) {                                         \
            int row = wr * 64 + m * 16 + lr;                                  \
            af[m] = *(const v8s*)(ab + row * 128 + ((64 + lg * 16) ^ ((row & 7) << 4))); \
        }                                                                     \
        _Pragma("unroll")                                                     \
        for (int n = 0; n < 3; n++) {                                         \
            int row = wc * 48 + n * 16 + lr;                                  \
            bf[n] = *(const v8s*)(bb + row * 128 + ((64 + lg * 16) ^ ((row & 7) << 4))); \
        }                                                                     \
        __builtin_amdgcn_sched_barrier(0);                                    \
        if (DOX2) PJ_XLOAD(RLOAD, (IT) + 2);                                  \
        __builtin_amdgcn_sched_barrier(0);                                    \
        if ((VMN) == 7) { asm volatile("s_waitcnt vmcnt(7)" ::: "memory"); }  \
        else if ((VMN) == 0) { asm volatile("s_waitcnt vmcnt(0)" ::: "memory"); } \
        __builtin_amdgcn_sched_barrier(0);                                    \
        if (DOCVT) PJ_CVT_WRITE(RCVT, (APAR) ^ 1);                            \
        __builtin_amdgcn_sched_barrier(0);                                    \
        __builtin_amdgcn_s_barrier();                                         \
        asm volatile("s_waitcnt lgkmcnt(0)" ::: "memory");                    \
        __builtin_amdgcn_sched_barrier(0);                                    \
        __builtin_amdgcn_s_setprio(1);                                        \
        _Pragma("unroll")                                                     \
        for (int m = 0; m < 4; m++)                                           \
            _Pragma("unroll")                                                 \
            for (int n = 0; n < 3; n++)                                       \
                acc[m][n] = MFMA16(af[m], bf[n], acc[m][n]);                  \
        __builtin_amdgcn_s_setprio(0);                                        \
        __builtin_amdgcn_s_barrier();                                         \
    }

#define PJ_TILE(APAR, BSLOT, BNSLOT, IT, RLOAD, RCVT, DOB2, DOX2, DOCVT, VMN) \
    PJ_PHASE1(APAR, BSLOT, BNSLOT, IT, DOB2)                                  \
    PJ_PHASE2(APAR, BSLOT, IT, RLOAD, RCVT, DOX2, DOCVT, VMN)

__launch_bounds__(512, 1)
__global__ void proj_kernel(const float* __restrict__ x, const ushort_t* __restrict__ WT,
                            ushort_t* __restrict__ q, ushort_t* __restrict__ kb,
                            ushort_t* __restrict__ vb) {
    __shared__ ushort_t abuf[2][8192];    // [128 m][64 k] bf16, byte ^ ((row&7)<<4)
    __shared__ ushort_t bbuf[3][12288];   // 3 rotating slots [192 n][64 k] bf16

    int bid = blockIdx.x;
    int xcd = bid & 7, t2 = bid >> 3;
    int nh = t2 & 1, mtl = t2 >> 1;       // (mtl,0)/(mtl,1): bids differ by 8
    int mtile = xcd * 16 + mtl;
    size_t m0 = (size_t)mtile * 128;
    int c0 = nh * 192;
    int tid = threadIdx.x, lane = tid & 63, wid = tid >> 6;   // wid 0..7
    int lg = lane >> 4, lr = lane & 15;
    int wr = wid >> 2, wc = wid & 3;      // 2 x 4 wave grid

    f32x4 acc[4][3];
    #pragma unroll
    for (int m = 0; m < 4; m++)
        #pragma unroll
        for (int n = 0; n < 3; n++) acc[m][n] = (f32x4){0.f, 0.f, 0.f, 0.f};

    // A loads (COALESCED): inst i covers rows 16wid+4i..+3; lanes 0-15 = one
    // row's 256B k-slice (16B/lane). cvt -> 8B ds_write at swizzled awb[i].
    const char* xsrc[4];
    int awb[4];
    #pragma unroll
    for (int i = 0; i < 4; i++) {
        int row = 16 * wid + 4 * i + (lane >> 4);
        xsrc[i] = (const char*)x + (m0 + row) * 8192 + (lane & 15) * 16;
        awb[i] = row * 128 + (((lane & 15) * 8) ^ ((row & 7) << 4));
    }

    // B stage: 24 segs of 1KB; wave stages segs 3wid..3wid+2 (pre-swizzled).
    const char* bsrc[3];
    #pragma unroll
    for (int i = 0; i < 3; i++) {
        int row = 8 * (3 * wid + i) + (lane >> 3);
        int col = ((lane & 7) * 16) ^ ((row & 7) << 4);
        bsrc[i] = (const char*)WT + (size_t)(c0 + row) * 4096 + col;
    }

    f32x4 xs0[4], xs1[4];
    // ---- prologue: B(0)->slot0, B(1)->slot1, x(0)->xs0, x(1)->xs1,
    //      vmcnt(4) (drain B0,B1,x0; x1 in flight), cvt A(0)->abuf0 ----
    #pragma unroll
    for (int i = 0; i < 3; i++)
        gld16(bsrc[i], (char*)bbuf + (wid * 3 + i) * 1024);
    #pragma unroll
    for (int i = 0; i < 3; i++)
        gld16(bsrc[i] + 128, (char*)bbuf + 24576 + (wid * 3 + i) * 1024);
    PJ_XLOAD(xs0, 0);
    PJ_XLOAD(xs1, 1);
    asm volatile("s_waitcnt vmcnt(4)" ::: "memory");
    PJ_CVT_WRITE(xs0, 0);
    asm volatile("s_waitcnt lgkmcnt(0)" ::: "memory");
    __builtin_amdgcn_s_barrier();

    // steady state (unroll 6 = lcm(Aparity 2, Bslots 3)), tiles 0..29:
    // tile t: A slot t%2, B slot t%3; issue B(t+2)->slot (t+2)%3;
    // load x(t+2)->xs[t%2]; cvt x(t+1) from xs[(t+1)%2] -> A slot (t+1)%2.
    for (int t6 = 0; t6 < 30; t6 += 6) {
        PJ_TILE(0, 0, 2, t6 + 0, xs0, xs1, 1, 1, 1, 7);
        PJ_TILE(1, 1, 0, t6 + 1, xs1, xs0, 1, 1, 1, 7);
        PJ_TILE(0, 2, 1, t6 + 2, xs0, xs1, 1, 1, 1, 7);
        PJ_TILE(1, 0, 2, t6 + 3, xs1, xs0, 1, 1, 1, 7);
        PJ_TILE(0, 1, 0, t6 + 4, xs0, xs1, 1, 1, 1, 7);
        PJ_TILE(1, 2, 1, t6 + 5, xs1, xs0, 1, 1, 1, 7);
    }
    // t=30: no new issues; cvt x(31)=xs1 -> A slot 1; vmcnt(0) drains all.
    PJ_TILE(0, 0, 0, 30, xs0, xs1, 0, 0, 1, 0);
    // t=31: pure compute (A slot 1, B slot 31%3=1).
    PJ_TILE(1, 1, 0, 31, xs1, xs0, 0, 0, 0, -1);

    // epilogue: D-frag lane holds row = 4*lg+e, col = lr within each 16x16 tile
    #pragma unroll
    for (int m = 0; m < 4; m++) {
        #pragma unroll
        for (int e = 0; e < 4; e++) {
            size_t row = m0 + (size_t)(wr * 64 + m * 16 + 4 * lg + e);
            int t = (int)(row & 4095);
            size_t base = (row >> 12) * 524288;
            #pragma unroll
            for (int n = 0; n < 3; n++) {
                int col = c0 + wc * 48 + n * 16 + lr;
                int w = col >> 7, d = col & 127;
                ushort_t val = f2bf(acc[m][n][e]);
                if (w == 0)
                    q[base + (size_t)(t >> 5) * 4096 + (d >> 4) * 512 + ((d >> 3) & 1) * 256 + (t & 31) * 8 + (d & 7)] = val;
                else if (w == 1)
                    kb[base + (size_t)(t >> 5) * 4096 + (d >> 4) * 512 + ((d >> 3) & 1) * 256 + (t & 31) * 8 + (d & 7)] = val;
                else
                    vb[base + (size_t)(t >> 4) * 2048 + (d >> 5) * 512 + ((t >> 3) & 1) * 256 + (d & 31) * 8 + (t & 7)] = val;
            }
        }
    }
}

// ---------------------------------------------------------------------------
// Kernel 3: causal flash attention (UNCHANGED — ~17-19 µs, ~900 TF effective).
// 32x32 MFMA, swapped QK^T (S^T = K·Q^T), O^T = V^T·P^T. 512 blocks x 4
// waves; waves split KV tiles mod 4, merge partials via LDS at the end.
// ---------------------------------------------------------------------------
__device__ __forceinline__ f32x16 zero16() {
    f32x16 z;
    #pragma unroll
    for (int i = 0; i < 16; i++) z[i] = 0.f;
    return z;
}

#define ATT_PVC(SV, BASE, VC, CNEXT)                                          \
    {                                                                         \
        unsigned a0 = f2bf2(SV[(BASE) + 0], SV[(BASE) + 1]);                  \
        unsigned a1 = f2bf2(SV[(BASE) + 2], SV[(BASE) + 3]);                  \
        unsigned b0 = f2bf2(SV[(BASE) + 4], SV[(BASE) + 5]);                  \
        unsigned b1 = f2bf2(SV[(BASE) + 6], SV[(BASE) + 7]);                  \
        unsigned snd0 = hi ? a0 : b0, snd1 = hi ? a1 : b1;                    \
        unsigned rcv0 = (unsigned)__shfl_xor((int)snd0, 32);                  \
        unsigned rcv1 = (unsigned)__shfl_xor((int)snd1, 32);                  \
        union { unsigned u[4]; v8s v; } pf;                                   \
        pf.u[0] = hi ? rcv0 : a0;                                             \
        pf.u[1] = hi ? rcv1 : a1;                                             \
        pf.u[2] = hi ? b0 : rcv0;                                             \
        pf.u[3] = hi ? b1 : rcv1;                                             \
        __builtin_amdgcn_s_setprio(1);                                        \
        _Pragma("unroll")                                                     \
        for (int dt = 0; dt < 4; dt++)                                        \
            accO[dt] = MFMA32(VC[dt], pf.v, accO[dt]);                        \
        __builtin_amdgcn_s_setprio(0);                                        \
        if ((CNEXT) >= 0) {                                                   \
            _Pragma("unroll")                                                 \
            for (int dt = 0; dt < 4; dt++)                                    \
                VC[dt] = *(const v8s*)(vg + (CNEXT) * 2048 + dt * 512);       \
        }                                                                     \
    }

__launch_bounds__(256, 2)
__global__ void attn_kernel(const ushort_t* __restrict__ q, const ushort_t* __restrict__ kb,
                            const ushort_t* __restrict__ vb, float* __restrict__ out) {
    __shared__ float obuf[4][4][16][64];   // [srcwave][dt][r][lane]  64 KB
    __shared__ float stat[2][4][64];       // m, l per wave per lane

    int bid = blockIdx.x;
    int xcd = bid & 7, rk = bid >> 3;
    int b = xcd >> 1;                       // batch pinned to XCD pair
    int g = rk * 2 + (xcd & 1);             // 0..127
    int qt = (g & 1) ? (g >> 1) : (127 - (g >> 1));   // alternate long/short
    int qt0 = qt * 32;
    int tid = threadIdx.x, lane = tid & 63, wid = tid >> 6;
    int hi = lane >> 5, lo = lane & 31;
    size_t bb = (size_t)b * 524288;
    int nt = (qt >> 1) + 1;
    const float cexp = 0.08838834764831845f * 1.4426950408889634f;  // scale*log2e

    // Q fragments (B-operand): lane holds Q[qt0+lo][ks*16+hi*8+j]
    v8s qf[8];
    {
        const ushort_t* qg = q + bb + (size_t)qt * 4096 + (size_t)lane * 8;
        #pragma unroll
        for (int ks = 0; ks < 8; ks++) qf[ks] = *(const v8s*)(qg + ks * 512);
    }

    f32x16 accO[4];
    #pragma unroll
    for (int dt = 0; dt < 4; dt++) accO[dt] = zero16();
    float mrun = -1e30f, lrun = 0.f;

    for (int t = wid; t < nt; t += 4) {
        const ushort_t* kg = kb + bb + (size_t)t * 8192 + (size_t)lane * 8;
        const ushort_t* vg = vb + bb + (size_t)t * 8192 + (size_t)lane * 8;

        // S^T = K·Q^T : two 32-kv subtiles, K-loop over d (8 steps of 16)
        f32x16 s0 = zero16(), s1 = zero16();
        __builtin_amdgcn_s_setprio(1);
        #pragma unroll
        for (int ks = 0; ks < 8; ks++) {
            v8s kf = *(const v8s*)(kg + ks * 512);
            s0 = MFMA32(kf, qf[ks], s0);
        }
        #pragma unroll
        for (int ks = 0; ks < 8; ks++) {
            v8s kf = *(const v8s*)(kg + 4096 + ks * 512);
            s1 = MFMA32(kf, qf[ks], s1);
        }
        __builtin_amdgcn_s_setprio(0);

        // V-frag rolling pair: c=0 and c=1 issued here, latency hidden by
        // the mask + softmax VALU below.
        v8s vA[4], vB[4];
        #pragma unroll
        for (int dt = 0; dt < 4; dt++) vA[dt] = *(const v8s*)(vg + dt * 512);
        #pragma unroll
        for (int dt = 0; dt < 4; dt++) vB[dt] = *(const v8s*)(vg + 2048 + dt * 512);

        // causal mask (diagonal tile only); S^T row index kv=(r&3)+8*(r>>2)+4*hi
        if (t == nt - 1) {
            int qrow = qt0 + lo;
            #pragma unroll
            for (int r = 0; r < 16; r++) {
                int kvb = t * 64 + (r & 3) + 8 * (r >> 2) + 4 * hi;
                if (kvb > qrow) s0[r] = -1e30f;
                if (kvb + 32 > qrow) s1[r] = -1e30f;
            }
        }

        // online softmax: lane owns q-row lo; only cross-lane op is xor-32
        float mx = s0[0];
        #pragma unroll
        for (int r = 1; r < 16; r++) mx = fmaxf(mx, s0[r]);
        #pragma unroll
        for (int r = 0; r < 16; r++) mx = fmaxf(mx, s1[r]);
        mx = fmaxf(mx, __shfl_xor(mx, 32));

        if (__any(mx > mrun + 62.7f)) {     // defer-max: skip rescale if growth < 8/cexp
            float mnew = fmaxf(mrun, mx);
            float fr = exp2f((mrun - mnew) * cexp);
            lrun *= fr;
            #pragma unroll
            for (int dt = 0; dt < 4; dt++)
                #pragma unroll
                for (int r = 0; r < 16; r++) accO[dt][r] *= fr;
            mrun = mnew;
        }
        float mc = mrun * cexp;
        float rs = 0.f;
        #pragma unroll
        for (int r = 0; r < 16; r++) { s0[r] = exp2f(fmaf(s0[r], cexp, -mc)); rs += s0[r]; }
        #pragma unroll
        for (int r = 0; r < 16; r++) { s1[r] = exp2f(fmaf(s1[r], cexp, -mc)); rs += s1[r]; }
        rs += __shfl_xor(rs, 32);
        lrun += rs;

        // PV: O^T += V^T·P^T ; P-frag assembled in-loop (1 shfl pair / chunk),
        // V-frags prefetched 2 chunks ahead into the just-consumed set.
        ATT_PVC(s0, 0, vA, 2);
        ATT_PVC(s0, 8, vB, 3);
        ATT_PVC(s1, 0, vA, -1);
        ATT_PVC(s1, 8, vB, -1);
    }

    // ---- merge the 4 waves' partial (m, l, O^T) states ----
    #pragma unroll
    for (int dt = 0; dt < 4; dt++)
        #pragma unroll
        for (int r = 0; r < 16; r++)
            obuf[wid][dt][r][lane] = accO[dt][r];
    stat[0][wid][lane] = mrun;
    stat[1][wid][lane] = lrun;
    __syncthreads();

    float m0 = stat[0][0][lane], m1 = stat[0][1][lane];
    float m2 = stat[0][2][lane], m3 = stat[0][3][lane];
    float m = fmaxf(fmaxf(m0, m1), fmaxf(m2, m3));
    float f0 = exp2f((m0 - m) * cexp), f1 = exp2f((m1 - m) * cexp);
    float f2 = exp2f((m2 - m) * cexp), f3 = exp2f((m3 - m) * cexp);
    float lsum = f0 * stat[1][0][lane] + f1 * stat[1][1][lane]
               + f2 * stat[1][2][lane] + f3 * stat[1][3][lane];
    float linv = 1.0f / lsum;

    float o[16];
    #pragma unroll
    for (int r = 0; r < 16; r++)
        o[r] = (f0 * obuf[0][wid][r][lane] + f1 * obuf[1][wid][r][lane]
              + f2 * obuf[2][wid][r][lane] + f3 * obuf[3][wid][r][lane]) * linv;

    // wave wid owns output cols wid*32..+32; col = wid*32 + 8a + 4hi + e
    float* orow = out + ((size_t)b * 4096 + qt0 + lo) * 128 + wid * 32 + 4 * hi;
    #pragma unroll
    for (int a = 0; a < 4; a++) {
        float4 vv;
        vv.x = o[4 * a + 0]; vv.y = o[4 * a + 1];
        vv.z = o[4 * a + 2]; vv.w = o[4 * a + 3];
        *(float4*)(orow + 8 * a) = vv;
    }
}

// ---------------------------------------------------------------------------
extern "C" void kernel_launch(void* const* d_in, const int* in_sizes, int n_in,
                              void* d_out, int out_size, void* d_ws, size_t ws_size,
                              hipStream_t stream) {
    const float* x  = (const float*)d_in[0];
    const float* Wq = (const float*)d_in[1];
    const float* Wk = (const float*)d_in[2];
    const float* Wv = (const float*)d_in[3];
    float* out = (float*)d_out;
    char* ws = (char*)d_ws;

    ushort_t* q  = (ushort_t*)(ws);               // 4 MB  q_blk
    ushort_t* kb = (ushort_t*)(ws + (4u << 20));  // 4 MB  k_blk
    ushort_t* vb = (ushort_t*)(ws + (8u << 20));  // 4 MB  v_blk
    ushort_t* WT = (ushort_t*)(ws + (12u << 20)); // 1.5MB WT bf16 [384][2048]

    transpose_w<<<dim3(96), dim3(256), 0, stream>>>(Wq, Wk, Wv, WT);
    proj_kernel<<<dim3(256), dim3(512), 0, stream>>>(x, WT, q, kb, vb);
    attn_kernel<<<dim3(512), dim3(256), 0, stream>>>(q, kb, vb, out);
}